// Round 8
// baseline (332.677 us; speedup 1.0000x reference)
//
#include <hip/hip_runtime.h>
#include <hip/hip_bf16.h>

#define N_FEAT 128
#define K_DIM 512

typedef __attribute__((ext_vector_type(8))) short short8;
typedef __attribute__((ext_vector_type(4))) float f32x4;

static __device__ __forceinline__ short f2bf(float f) {
    // round-to-nearest-even f32 -> bf16
    unsigned u = __float_as_uint(f);
    unsigned r = (u + 0x7FFFu + ((u >> 16) & 1u)) >> 16;
    return (short)r;
}

static __device__ __forceinline__ float2 bfp(unsigned u) {
    // unpack 2 bf16 (packed little-endian) -> 2 f32
    return make_float2(__uint_as_float(u << 16), __uint_as_float(u & 0xFFFF0000u));
}

static __device__ __forceinline__ int load_idx(const void* e, int i, int is64) {
    return is64 ? (int)((const long long*)e)[i] : ((const int*)e)[i];
}

// ---------------------------------------------------------------------------
// setup: Wt transpose+bf16, zero cnt, detect index dtype (block 0)
__global__ __launch_bounds__(256) void k_setup(const float* __restrict__ W,
                                               short* __restrict__ Wt,
                                               int* __restrict__ cnt, int n,
                                               const long long* __restrict__ e,
                                               long long nmax, int* __restrict__ flag) {
    __shared__ int ok;
    int i = blockIdx.x * 256 + threadIdx.x;
    if (i < K_DIM * N_FEAT) {
        int k = i >> 7, c = i & 127;
        Wt[c * K_DIM + k] = f2bf(W[i]);
    }
    if (i < n) cnt[i] = 0;
    if (blockIdx.x == 0) {
        if (threadIdx.x == 0) ok = 1;
        __syncthreads();
        long long val = e[threadIdx.x];
        if (val < 0 || val >= nmax) ok = 0;  // benign race
        __syncthreads();
        if (threadIdx.x == 0) *flag = ok;
    }
}

// histogram of dst (self-loop +1 applied in dinv only)
__global__ void k_hist(const void* __restrict__ eidx, const int* __restrict__ flagp,
                       int E, int* __restrict__ cnt) {
    int i = blockIdx.x * 256 + threadIdx.x;
    if (i >= E) return;
    int is64 = *flagp;
    int dst = load_idx(eidx, E + i, is64);
    atomicAdd(&cnt[dst], 1);
}

// ---------------------------------------------------------------------------
// hierarchical exclusive scan (3 kernels); scan1 also computes dinv
__global__ __launch_bounds__(256) void k_scan1(const int* __restrict__ cnt,
                                               int* __restrict__ rowstart,
                                               int* __restrict__ btot,
                                               float* __restrict__ dinv, int n) {
    __shared__ int wtot[4];
    int tid = threadIdx.x, wid = tid >> 6, lane = tid & 63;
    int i = blockIdx.x * 256 + tid;
    int v = (i < n) ? cnt[i] : 0;
    if (i < n) dinv[i] = rsqrtf(1.0f + (float)v);
    int x = v;
#pragma unroll
    for (int off = 1; off < 64; off <<= 1) {
        int t = __shfl_up(x, off);
        if (lane >= off) x += t;
    }
    if (lane == 63) wtot[wid] = x;
    __syncthreads();
    if (tid == 0) {
        int a = wtot[0], b = wtot[1], c = wtot[2], d = wtot[3];
        wtot[0] = 0; wtot[1] = a; wtot[2] = a + b; wtot[3] = a + b + c;
        btot[blockIdx.x] = a + b + c + d;
    }
    __syncthreads();
    if (i < n) rowstart[i] = wtot[wid] + x - v;
}

__global__ __launch_bounds__(256) void k_scan2(const int* __restrict__ btot,
                                               int* __restrict__ boff,
                                               int* __restrict__ rowstart, int nb, int n) {
    __shared__ int wtot[4];
    int tid = threadIdx.x, wid = tid >> 6, lane = tid & 63;
    int v = (tid < nb) ? btot[tid] : 0;
    int x = v;
#pragma unroll
    for (int off = 1; off < 64; off <<= 1) {
        int t = __shfl_up(x, off);
        if (lane >= off) x += t;
    }
    if (lane == 63) wtot[wid] = x;
    __syncthreads();
    if (tid == 0) {
        int a = wtot[0], b = wtot[1], c = wtot[2];
        wtot[0] = 0; wtot[1] = a; wtot[2] = a + b; wtot[3] = a + b + c;
    }
    __syncthreads();
    int excl = wtot[wid] + x - v;
    if (tid < nb) boff[tid] = excl;
    if (tid == nb - 1) rowstart[n] = excl + v;
}

__global__ void k_scan3(int* __restrict__ rowstart, int* __restrict__ cursor,
                        const int* __restrict__ boff, int n) {
    int i = blockIdx.x * 256 + threadIdx.x;
    if (i < n) {
        int r = rowstart[i] + boff[blockIdx.x];
        rowstart[i] = r;
        cursor[i] = r;
    }
}

// scatter edge ids into CSR slots (int atomics on 200KB cursor array only)
__global__ void k_fill(const void* __restrict__ eidx, const int* __restrict__ flagp,
                       int E, int* __restrict__ cursor, int* __restrict__ col) {
    int e = blockIdx.x * 256 + threadIdx.x;
    if (e >= E) return;
    int is64 = *flagp;
    int src = load_idx(eidx, e, is64);
    int dst = load_idx(eidx, E + e, is64);
    int slot = atomicAdd(&cursor[dst], 1);
    col[slot] = src;
}

// ---------------------------------------------------------------------------
// h = x @ W via bf16 MFMA — barrier-free, LDS-free.
// Each wave owns a 16-row x 128-col output strip; A read directly from global
// (rows are wave-exclusive, read exactly once), B (Wt) read from L2 (128KB,
// resident). 8 MFMAs per K-step, 16 K-steps, loads pipeline across the
// unrolled loop with no barriers to drain.
__global__ __launch_bounds__(256) void k_gemm(const float* __restrict__ x,
                                              const short* __restrict__ Wt,
                                              unsigned short* __restrict__ h, int n) {
    int tid = threadIdx.x;
    int wave = tid >> 6, lane = tid & 63;
    int lr = lane & 15, kg = lane >> 4;
    int row = blockIdx.x * 64 + wave * 16 + lr;  // A row this lane reads
    int rowc = row < n ? row : n - 1;            // clamp (dup loads harmless)
    const float* xr = x + (size_t)rowc * K_DIM;

    f32x4 acc[8];
#pragma unroll
    for (int t = 0; t < 8; t++) acc[t] = (f32x4)(0.0f);

#pragma unroll 4
    for (int ks = 0; ks < 16; ks++) {
        int k0 = ks * 32 + kg * 8;
        float4 a0 = *reinterpret_cast<const float4*>(xr + k0);
        float4 a1 = *reinterpret_cast<const float4*>(xr + k0 + 4);
        short8 af;
        af[0] = f2bf(a0.x); af[1] = f2bf(a0.y); af[2] = f2bf(a0.z); af[3] = f2bf(a0.w);
        af[4] = f2bf(a1.x); af[5] = f2bf(a1.y); af[6] = f2bf(a1.z); af[7] = f2bf(a1.w);
#pragma unroll
        for (int t = 0; t < 8; t++) {
            short8 b = *reinterpret_cast<const short8*>(Wt + (size_t)(t * 16 + lr) * K_DIM + k0);
            acc[t] = __builtin_amdgcn_mfma_f32_16x16x32_bf16(af, b, acc[t], 0, 0, 0);
        }
    }

    // C/D layout: col = lane&15, row = (lane>>4)*4 + r
    int orow0 = blockIdx.x * 64 + wave * 16 + kg * 4;
#pragma unroll
    for (int r = 0; r < 4; r++) {
        int orow = orow0 + r;
        if (orow < n) {
#pragma unroll
            for (int t = 0; t < 8; t++) {
                h[(size_t)orow * N_FEAT + t * 16 + lr] = (unsigned short)f2bf(acc[t][r]);
            }
        }
    }
}

// ---------------------------------------------------------------------------
// aggregate (bf16 h, unroll-4 gathers) + bias + log_softmax, one wave/node
__global__ __launch_bounds__(256) void k_agg(const int* __restrict__ rowstart,
                                             const int* __restrict__ col,
                                             const float* __restrict__ dinv,
                                             const unsigned* __restrict__ h,
                                             const float* __restrict__ bias,
                                             float* __restrict__ out, int n) {
    int wid = threadIdx.x >> 6, lane = threadIdx.x & 63;
    int v = blockIdx.x * 4 + wid;
    if (v >= n) return;
    float dv = dinv[v];
    float2 hself = bfp(h[(size_t)v * 64 + lane]);
    float sl = dv * dv;
    float a0 = hself.x * sl;
    float a1 = hself.y * sl;

    int e = rowstart[v], eend = rowstart[v + 1];
    for (; e + 4 <= eend; e += 4) {
        int s0 = col[e], s1 = col[e + 1], s2 = col[e + 2], s3 = col[e + 3];
        float w0 = dinv[s0], w1 = dinv[s1], w2 = dinv[s2], w3 = dinv[s3];
        unsigned g0 = h[(size_t)s0 * 64 + lane];
        unsigned g1 = h[(size_t)s1 * 64 + lane];
        unsigned g2 = h[(size_t)s2 * 64 + lane];
        unsigned g3 = h[(size_t)s3 * 64 + lane];
        w0 *= dv; w1 *= dv; w2 *= dv; w3 *= dv;
        float2 f0 = bfp(g0), f1 = bfp(g1), f2 = bfp(g2), f3 = bfp(g3);
        a0 += f0.x * w0; a1 += f0.y * w0;
        a0 += f1.x * w1; a1 += f1.y * w1;
        a0 += f2.x * w2; a1 += f2.y * w2;
        a0 += f3.x * w3; a1 += f3.y * w3;
    }
    for (; e < eend; e++) {
        int s0 = col[e];
        float w = dinv[s0] * dv;
        float2 f = bfp(h[(size_t)s0 * 64 + lane]);
        a0 += f.x * w;
        a1 += f.y * w;
    }
    float2 bb = reinterpret_cast<const float2*>(bias)[lane];
    a0 += bb.x;
    a1 += bb.y;

    float m = fmaxf(a0, a1);
#pragma unroll
    for (int sh = 32; sh; sh >>= 1) m = fmaxf(m, __shfl_xor(m, sh));
    float sum = __expf(a0 - m) + __expf(a1 - m);
#pragma unroll
    for (int sh = 32; sh; sh >>= 1) sum += __shfl_xor(sum, sh);
    float lse = m + __logf(sum);
    reinterpret_cast<float2*>(out + (size_t)v * N_FEAT)[lane] =
        make_float2(a0 - lse, a1 - lse);
}

// ---------------------------------------------------------------------------
extern "C" void kernel_launch(void* const* d_in, const int* in_sizes, int n_in,
                              void* d_out, int out_size, void* d_ws, size_t ws_size,
                              hipStream_t stream) {
    const float* x = (const float*)d_in[0];
    const void* eidx = d_in[1];
    const float* W = (const float*)d_in[2];
    const float* b = (const float*)d_in[3];
    int n = in_sizes[0] / K_DIM;   // 50000
    int E = in_sizes[1] / 2;       // 800000
    float* out = (float*)d_out;

    char* ws = (char*)d_ws;
    int* flagp = (int*)ws;                        // @0
    int* btot = (int*)(ws + 256);                 // 256 ints
    int* boff = (int*)(ws + 2048);                // 256 ints
    int* cnt = (int*)(ws + 8192);                 // n ints
    int* rowstart = (int*)(ws + 212992);          // n+1 ints
    int* cursor = (int*)(ws + 417792);            // n ints
    float* dinv = (float*)(ws + 622592);          // n f32
    short* Wt = (short*)(ws + 827392);            // 128*512 bf16
    int* col = (int*)(ws + 962560);               // E ints = 3.2MB
    unsigned short* h = (unsigned short*)(ws + 4194304);  // n*128 bf16 = 12.8MB

    int nbN = (n + 255) / 256;                    // 196
    int nbS = nbN > 256 ? nbN : 256;              // covers 65536 Wt elems too

    k_setup<<<nbS, 256, 0, stream>>>(W, Wt, cnt, n, (const long long*)eidx,
                                     (long long)n, flagp);
    k_hist<<<(E + 255) / 256, 256, 0, stream>>>(eidx, flagp, E, cnt);
    k_scan1<<<nbN, 256, 0, stream>>>(cnt, rowstart, btot, dinv, n);
    k_scan2<<<1, 256, 0, stream>>>(btot, boff, rowstart, nbN, n);
    k_scan3<<<nbN, 256, 0, stream>>>(rowstart, cursor, boff, n);
    k_fill<<<(E + 255) / 256, 256, 0, stream>>>(eidx, flagp, E, cursor, col);
    k_gemm<<<(n + 63) / 64, 256, 0, stream>>>(x, Wt, h, n);
    k_agg<<<(n + 3) / 4, 256, 0, stream>>>(rowstart, col, dinv,
                                           reinterpret_cast<const unsigned*>(h), b, out, n);
}